// Round 15
// baseline (1216.302 us; speedup 1.0000x reference)
//
#include <hip/hip_runtime.h>

// ---- sizes (fixed by the problem) ----
#define Bsz 64
#define Tsz 64
#define Vsz 32000
#define DEsz 512
#define DDsz 1024
#define DCsz 512
#define DIN 1024     // DE+DC
#define G3 3072      // 3*DD

typedef unsigned short u16;
typedef unsigned int   u32;
typedef unsigned long long u64;
typedef __attribute__((ext_vector_type(8))) __bf16 bf16x8;
typedef __attribute__((ext_vector_type(4))) float f32x4;

__device__ __forceinline__ u16 f2bf(float f) {
    union { float f; unsigned int u; } v; v.f = f;
    unsigned int r = v.u + 0x7fffu + ((v.u >> 16) & 1u);  // RNE
    return (u16)(r >> 16);
}

__device__ __forceinline__ void gload_lds16(const u16* g, u16* l) {
    __builtin_amdgcn_global_load_lds(
        (const __attribute__((address_space(1))) void*)g,
        (__attribute__((address_space(3))) void*)l, 16, 0, 0);
}

__device__ __forceinline__ float fast_sigmoid(float x) {
    float xc = fminf(fmaxf(x, -30.f), 30.f);
    return 1.f / (1.f + __expf(-xc));
}
__device__ __forceinline__ float fast_tanh(float x) {
    float xc = fminf(fmaxf(x, -15.f), 15.f);
    float e = __expf(2.f * xc);
    return (e - 1.f) / (e + 1.f);
}

// ---------- f32 -> bf16 bulk convert ----------
__global__ void f32_to_bf16(const float* __restrict__ src, u16* __restrict__ dst, long n) {
    long i = ((long)blockIdx.x * blockDim.x + threadIdx.x) * 4;
    if (i + 3 < n) {
        float4 v = *(const float4*)&src[i];
        dst[i + 0] = f2bf(v.x);
        dst[i + 1] = f2bf(v.y);
        dst[i + 2] = f2bf(v.z);
        dst[i + 3] = f2bf(v.w);
    }
}

// ---------- build X = concat(emb[token], context) bf16, row = b*T + t ----------
__global__ void build_x(const float* __restrict__ emb, const float* __restrict__ ctx,
                        const int* __restrict__ labels, const int* __restrict__ bos,
                        u16* __restrict__ X) {
    int i = blockIdx.x;            // 0..4095 = b*64 + t
    int b = i >> 6;
    int t = i & 63;
    int tok = (t == 0) ? *bos : labels[b * Tsz + (t - 1)];
    const float* s0 = emb + (long)tok * DEsz;
    const float* s1 = ctx + (long)b * DCsz;
    u16* dst = X + (long)i * DIN;
    for (int c = threadIdx.x; c < DEsz; c += blockDim.x) {
        dst[c]        = f2bf(s0[c]);
        dst[DEsz + c] = f2bf(s1[c]);
    }
}

// ---------- 128x128 GEMM: C = A . B^T + bias; LDS-staged FULL-LINE stores ----------
__global__ __launch_bounds__(256) void gemm128(
    const u16* __restrict__ A, const u16* __restrict__ Bm,
    const float* __restrict__ bias, float* __restrict__ C,
    int N, int K, int mblk)
{
    __shared__ __align__(16) u16 As[128 * 32];
    __shared__ __align__(16) u16 Bs[128 * 32];
    __shared__ __align__(16) float stage[32 * 132];   // full-line writeback staging
    const int tid  = threadIdx.x;
    const int wave = tid >> 6;
    const int lane = tid & 63;
    const int wm = wave >> 1, wn = wave & 1;

    int nwg = gridDim.x;
    int wg  = blockIdx.x;
    int cpx = nwg >> 3;                      // nwg % 8 == 0 by construction
    wg = (wg & 7) * cpx + (wg >> 3);         // XCD-aware swizzle (bijective)
    const int bm = (wg % mblk) * 128;        // bm fastest -> B-panel reuse
    const int bn = (wg / mblk) * 128;

    const int sr = tid >> 2;
    const int sc = (tid & 3) * 8;
    const u16* ga0 = A  + (long)(bm + sr) * K + sc;
    const u16* ga1 = A  + (long)(bm + 64 + sr) * K + sc;
    const u16* gb0 = Bm + (long)(bn + sr) * K + sc;
    const u16* gb1 = Bm + (long)(bn + 64 + sr) * K + sc;
    u16* la0 = As + tid * 8;
    u16* la1 = As + 2048 + tid * 8;
    u16* lb0 = Bs + tid * 8;
    u16* lb1 = Bs + 2048 + tid * 8;

    const int fr = lane & 15;
    const int kh = (lane >> 4) * 8;

    f32x4 acc[4][4];
    #pragma unroll
    for (int i = 0; i < 4; ++i)
        #pragma unroll
        for (int j = 0; j < 4; ++j) acc[i][j] = f32x4{0.f, 0.f, 0.f, 0.f};

    for (int k0 = 0; k0 < K; k0 += 32) {
        gload_lds16(ga0 + k0, la0);
        gload_lds16(ga1 + k0, la1);
        gload_lds16(gb0 + k0, lb0);
        gload_lds16(gb1 + k0, lb1);
        __syncthreads();
        bf16x8 af[4], bf[4];
        #pragma unroll
        for (int mi = 0; mi < 4; ++mi)
            af[mi] = *(const bf16x8*)&As[(wm * 64 + mi * 16 + fr) * 32 + kh];
        #pragma unroll
        for (int ni = 0; ni < 4; ++ni)
            bf[ni] = *(const bf16x8*)&Bs[(wn * 64 + ni * 16 + fr) * 32 + kh];
        #pragma unroll
        for (int mi = 0; mi < 4; ++mi)
            #pragma unroll
            for (int ni = 0; ni < 4; ++ni)
                acc[mi][ni] = __builtin_amdgcn_mfma_f32_16x16x32_bf16(af[mi], bf[ni], acc[mi][ni], 0, 0, 0);
        __syncthreads();
    }

    // epilogue: stage each 32x128 chunk in LDS, write back as full cache lines
    const int r0 = (lane >> 4) * 4;
    float bv[4];
    #pragma unroll
    for (int ni = 0; ni < 4; ++ni) bv[ni] = bias[bn + wn * 64 + ni * 16 + fr];

    #pragma unroll
    for (int mi = 0; mi < 4; ++mi) {
        __syncthreads();
        #pragma unroll
        for (int ni = 0; ni < 4; ++ni) {
            int scol = wn * 64 + ni * 16 + fr;
            #pragma unroll
            for (int j = 0; j < 4; ++j)
                stage[(wm * 16 + r0 + j) * 132 + scol] = acc[mi][ni][j] + bv[ni];
        }
        __syncthreads();
        #pragma unroll
        for (int p = 0; p < 4; ++p) {
            int idx  = p * 256 + tid;           // float4 unit 0..1023
            int srow = idx >> 5;                // 0..31
            int sc4  = (idx & 31) * 4;          // 0..124
            f32x4 v = *(const f32x4*)&stage[srow * 132 + sc4];
            int grow = bm + mi * 16 + (srow & 15) + (srow >> 4) * 64;
            __builtin_nontemporal_store(v, (f32x4*)&C[(long)grow * N + bn + sc4]);
        }
    }
}

// ---------- persistent GRU v10: W in REGISTERS (zero LDS in K-loop) ----------
// 64 blocks x 256 thr. Block owns 16 hidden cols x 3 gates; wave w owns batch
// rows [16w,16w+16). Each lane holds its 96 W B-fragments in 384 VGPRs,
// loaded once. K-loop: fully unrolled, MFMA on register W + coalesced hT loads.
// hT [t][kb(32)][b(64)][ki(32)]; dual store (hT atomic + hst nontemporal).
#define PF 8
__global__ __launch_bounds__(256) void gru_persist(
    const u16* __restrict__ Whh,     // [3072][1024] bf16
    const float* __restrict__ bhh,   // [3072]
    const float* __restrict__ gi,    // [4096][3072] f32, row = b*T + t
    const float* __restrict__ initp, // [1024]
    u16* __restrict__ hst,           // [4096][1024] bf16 row-major (b*T+t)
    u16* __restrict__ hT,            // [64][32][64][32] bf16 k-major
    int* __restrict__ arr,           // 8 arrival counters, 64B apart, zeroed
    int* __restrict__ rel)           // 8 release lines, 64B apart, zeroed
{
    __builtin_amdgcn_fence(__ATOMIC_ACQUIRE, "agent");   // inv stale L2 (prior replay)

    __shared__ __align__(16) u16 h0l[1024];
    const int tid  = threadIdx.x;
    const int w    = tid >> 6;       // wave 0..3 -> batch quarter
    const int lane = tid & 63;
    const int c0   = blockIdx.x * 16;
    const int fr   = lane & 15;
    const int kh   = (lane >> 4) * 8;
    const int r0   = (lane >> 4) * 4;
    const int kb_s = blockIdx.x >> 1;            // this block's k-block in hT
    const int kio  = (blockIdx.x & 1) * 16;      // ki offset within k-block

    // W fragments -> registers (once). wX[k] = B-frag of gate X, k-step k.
    bf16x8 wR[32], wZ[32], wN[32];
    {
        const u16* w0 = Whh + ((long)(c0 + fr)) * DDsz + kh;             // gate r
        const u16* w1 = Whh + ((long)(DDsz + c0 + fr)) * DDsz + kh;      // gate z
        const u16* w2 = Whh + ((long)(2 * DDsz + c0 + fr)) * DDsz + kh;  // gate n
        #pragma unroll
        for (int k = 0; k < 32; ++k) {
            wR[k] = *(const bf16x8*)(w0 + k * 32);
            wZ[k] = *(const bf16x8*)(w1 + k * 32);
            wN[k] = *(const bf16x8*)(w2 + k * 32);
        }
    }
    #pragma unroll
    for (int i = 0; i < 4; ++i) h0l[tid * 4 + i] = f2bf(initp[tid * 4 + i]);
    __syncthreads();

    float hc[4];
    { float v = initp[c0 + fr];
      #pragma unroll
      for (int j = 0; j < 4; ++j) hc[j] = v; }
    const float bR = bhh[c0 + fr];
    const float bZ = bhh[DDsz + c0 + fr];
    const float bN = bhh[2 * DDsz + c0 + fr];

    // gi(t=0) prefetch: row = b*T + 0
    float gir[4], giz[4], gin_[4];
    #pragma unroll
    for (int j = 0; j < 4; ++j) {
        long gib = ((long)(w * 16 + r0 + j) * Tsz) * G3 + c0 + fr;
        gir[j]  = gi[gib];
        giz[j]  = gi[gib + DDsz];
        gin_[j] = gi[gib + 2 * DDsz];
    }

    for (int t = 0; t < Tsz; ++t) {
        f32x4 acc[3];
        #pragma unroll
        for (int g = 0; g < 3; ++g) acc[g] = f32x4{0.f, 0.f, 0.f, 0.f};

        if (t == 0) {
            #pragma unroll
            for (int k = 0; k < 32; ++k) {
                bf16x8 a = *(const bf16x8*)&h0l[k * 32 + kh];
                acc[0] = __builtin_amdgcn_mfma_f32_16x16x32_bf16(a, wR[k], acc[0], 0, 0, 0);
                acc[1] = __builtin_amdgcn_mfma_f32_16x16x32_bf16(a, wZ[k], acc[1], 0, 0, 0);
                acc[2] = __builtin_amdgcn_mfma_f32_16x16x32_bf16(a, wN[k], acc[2], 0, 0, 0);
            }
        } else {
            // COALESCED: k-step reads 1024B contiguous per wave from hT(t-1)
            const u16* q0 = hT + ((long)(t - 1) * 32 * 64 + w * 16) * 32 + fr * 32 + kh;
            bf16x8 p0[PF];
            #pragma unroll
            for (int p = 0; p < PF; ++p) p0[p] = *(const bf16x8*)(q0 + p * 2048);
            #pragma unroll
            for (int k = 0; k < 32; ++k) {
                bf16x8 a = p0[k & (PF - 1)];
                if (k < 32 - PF) p0[k & (PF - 1)] = *(const bf16x8*)(q0 + (k + PF) * 2048);
                acc[0] = __builtin_amdgcn_mfma_f32_16x16x32_bf16(a, wR[k], acc[0], 0, 0, 0);
                acc[1] = __builtin_amdgcn_mfma_f32_16x16x32_bf16(a, wZ[k], acc[1], 0, 0, 0);
                acc[2] = __builtin_amdgcn_mfma_f32_16x16x32_bf16(a, wN[k], acc[2], 0, 0, 0);
            }
        }

        // gates + dual h store
        #pragma unroll
        for (int j = 0; j < 4; ++j) {
            int b = w * 16 + r0 + j;
            float r = fast_sigmoid(gir[j] + acc[0][j] + bR);
            float z = fast_sigmoid(giz[j] + acc[1][j] + bZ);
            float n = fast_tanh(gin_[j] + r * (acc[2][j] + bN));
            float h = (1.f - z) * n + z * hc[j];
            hc[j] = h;
            int hb = (int)f2bf(h);
            int pb = __shfl_xor(hb, 1, 64);        // partner column bits
            if (!(fr & 1)) {
                u32 val = ((u32)pb << 16) | (u32)hb;
                // k-major (recurrence; cross-block coherent write-through)
                __hip_atomic_store(
                    (u32*)(hT + (((long)t * 32 + kb_s) * 64 + b) * 32 + kio + fr), val,
                    __ATOMIC_RELAXED, __HIP_MEMORY_SCOPE_AGENT);
                // row-major (logits GEMM input; visible at dispatch boundary)
                __builtin_nontemporal_store(
                    val, (u32*)(hst + ((long)b * Tsz + t) * DDsz + c0 + fr));
            }
        }

        if (t != Tsz - 1) {
            asm volatile("" ::: "memory");   // pin: h stores issue before gi loads

            // gi(t+1): 12 loads stay IN FLIGHT across the barrier
            int tp = t + 1;
            #pragma unroll
            for (int j = 0; j < 4; ++j) {
                long gib = ((long)(w * 16 + r0 + j) * Tsz + tp) * G3 + c0 + fr;
                gir[j]  = gi[gib];
                giz[j]  = gi[gib + DDsz];
                gin_[j] = gi[gib + 2 * DDsz];
            }

            // drain everything older than the 12 gi loads (= all 8 h stores)
            asm volatile("s_waitcnt vmcnt(12)" ::: "memory");
            __builtin_amdgcn_s_barrier();            // all waves' stores drained
            if (tid == 0) {
                __hip_atomic_fetch_add(&arr[(blockIdx.x & 7) << 4], 1,
                                       __ATOMIC_RELAXED, __HIP_MEMORY_SCOPE_AGENT);
                if (blockIdx.x == 0) {
                    const int tgt = 64 * (t + 1);
                    for (;;) {
                        int s = 0;
                        #pragma unroll
                        for (int g = 0; g < 8; ++g)
                            s += __hip_atomic_load(&arr[g << 4], __ATOMIC_RELAXED,
                                                   __HIP_MEMORY_SCOPE_AGENT);
                        if (s >= tgt) break;
                    }
                    #pragma unroll
                    for (int g = 0; g < 8; ++g)
                        __hip_atomic_store(&rel[g << 4], t + 1,
                                           __ATOMIC_RELAXED, __HIP_MEMORY_SCOPE_AGENT);
                } else {
                    while (__hip_atomic_load(&rel[(blockIdx.x & 7) << 4],
                                             __ATOMIC_RELAXED,
                                             __HIP_MEMORY_SCOPE_AGENT) < t + 1) { }
                }
            }
            __syncthreads();   // full drain + fence: safe restart of K-loop
        }
    }
}

extern "C" void kernel_launch(void* const* d_in, const int* in_sizes, int n_in,
                              void* d_out, int out_size, void* d_ws, size_t ws_size,
                              hipStream_t stream) {
    const float* ctx    = (const float*)d_in[0];
    const int*   labels = (const int*)  d_in[1];
    const float* emb    = (const float*)d_in[2];
    const float* W_ih   = (const float*)d_in[3];
    const float* b_ih   = (const float*)d_in[4];
    const float* W_hh   = (const float*)d_in[5];
    const float* b_hh   = (const float*)d_in[6];
    const float* initp  = (const float*)d_in[7];
    const float* W_out  = (const float*)d_in[8];
    const float* b_out  = (const float*)d_in[9];
    const int*   bos    = (const int*)  d_in[10];
    float* out = (float*)d_out;

    char* ws = (char*)d_ws;
    u16*   Xbf    = (u16*)  (ws + 0L);            //  8,388,608
    float* gi     = (float*)(ws + 8388608L);      // 50,331,648
    u16*   hst    = (u16*)  (ws + 58720256L);     //  8,388,608  (row-major)
    u16*   hT     = (u16*)  (ws + 67108864L);     //  8,388,608  (k-major)
    u16*   Wih_b  = (u16*)  (ws + 75497472L);     //  6,291,456
    u16*   Whh_b  = (u16*)  (ws + 81788928L);     //  6,291,456
    u16*   Wout_b = (u16*)  (ws + 88080384L);     // 65,536,000 -> 153,616,384
    int*   arr    = (int*)  (ws + 153616384L);    // 512 B arrival counters
    int*   rel    = (int*)  (ws + 153617408L);    // 512 B release lines

    (void)hipMemsetAsync(arr, 0, 2048, stream);   // zero arr + rel

    long n1 = (long)G3 * DIN;          // 3,145,728
    long n2 = (long)Vsz * DDsz;        // 32,768,000
    f32_to_bf16<<<(unsigned)(n1 / 4 / 256), 256, 0, stream>>>(W_ih, Wih_b, n1);
    f32_to_bf16<<<(unsigned)(n1 / 4 / 256), 256, 0, stream>>>(W_hh, Whh_b, n1);
    f32_to_bf16<<<(unsigned)(n2 / 4 / 256), 256, 0, stream>>>(W_out, Wout_b, n2);

    build_x<<<Bsz * Tsz, 128, 0, stream>>>(emb, ctx, labels, bos, Xbf);

    // gi = X @ W_ih^T + b_ih   (4096 x 3072), grid 768 (%8==0)
    gemm128<<<(4096 / 128) * (G3 / 128), 256, 0, stream>>>(
        Xbf, Wih_b, b_ih, gi, G3, DIN, 4096 / 128);

    // 64 recurrent steps in ONE persistent launch
    gru_persist<<<DDsz / 16, 256, 0, stream>>>(Whh_b, b_hh, gi, initp,
                                               hst, hT, arr, rel);

    // logits = states @ W_out^T + b_out -> out[b][t][v] (linear rows), grid 8000
    gemm128<<<(4096 / 128) * (Vsz / 128), 256, 0, stream>>>(
        hst, Wout_b, b_out, out, Vsz, DDsz, 4096 / 128);
}

// Round 16
// 957.595 us; speedup vs baseline: 1.2702x; 1.2702x over previous
//
#include <hip/hip_runtime.h>

// ---- sizes (fixed by the problem) ----
#define Bsz 64
#define Tsz 64
#define Vsz 32000
#define DEsz 512
#define DDsz 1024
#define DCsz 512
#define DIN 1024     // DE+DC
#define G3 3072      // 3*DD
#define NCONS 192    // consumer blocks
#define NTT 250      // N tiles (32000/128)
#define NMT 32       // M tiles (4096/128)

typedef unsigned short u16;
typedef unsigned int   u32;
typedef unsigned long long u64;
typedef __attribute__((ext_vector_type(8))) __bf16 bf16x8;
typedef __attribute__((ext_vector_type(4))) float f32x4;

__device__ __forceinline__ u16 f2bf(float f) {
    union { float f; unsigned int u; } v; v.f = f;
    unsigned int r = v.u + 0x7fffu + ((v.u >> 16) & 1u);  // RNE
    return (u16)(r >> 16);
}

__device__ __forceinline__ void gload_lds16(const u16* g, u16* l) {
    __builtin_amdgcn_global_load_lds(
        (const __attribute__((address_space(1))) void*)g,
        (__attribute__((address_space(3))) void*)l, 16, 0, 0);
}

__device__ __forceinline__ float fast_sigmoid(float x) {
    float xc = fminf(fmaxf(x, -30.f), 30.f);
    return 1.f / (1.f + __expf(-xc));
}
__device__ __forceinline__ float fast_tanh(float x) {
    float xc = fminf(fmaxf(x, -15.f), 15.f);
    float e = __expf(2.f * xc);
    return (e - 1.f) / (e + 1.f);
}

// ---------- f32 -> bf16 bulk convert ----------
__global__ void f32_to_bf16(const float* __restrict__ src, u16* __restrict__ dst, long n) {
    long i = ((long)blockIdx.x * blockDim.x + threadIdx.x) * 4;
    if (i + 3 < n) {
        float4 v = *(const float4*)&src[i];
        dst[i + 0] = f2bf(v.x);
        dst[i + 1] = f2bf(v.y);
        dst[i + 2] = f2bf(v.z);
        dst[i + 3] = f2bf(v.w);
    }
}

// ---------- build X = concat(emb[token], context) bf16, row = b*T + t ----------
__global__ void build_x(const float* __restrict__ emb, const float* __restrict__ ctx,
                        const int* __restrict__ labels, const int* __restrict__ bos,
                        u16* __restrict__ X) {
    int i = blockIdx.x;            // 0..4095 = b*64 + t
    int b = i >> 6;
    int t = i & 63;
    int tok = (t == 0) ? *bos : labels[b * Tsz + (t - 1)];
    const float* s0 = emb + (long)tok * DEsz;
    const float* s1 = ctx + (long)b * DCsz;
    u16* dst = X + (long)i * DIN;
    for (int c = threadIdx.x; c < DEsz; c += blockDim.x) {
        dst[c]        = f2bf(s0[c]);
        dst[DEsz + c] = f2bf(s1[c]);
    }
}

// ---------- 128x128 GEMM (used for gi): LDS-staged FULL-LINE stores ----------
__global__ __launch_bounds__(256) void gemm128(
    const u16* __restrict__ A, const u16* __restrict__ Bm,
    const float* __restrict__ bias, float* __restrict__ C,
    int N, int K, int mblk)
{
    __shared__ __align__(16) u16 As[128 * 32];
    __shared__ __align__(16) u16 Bs[128 * 32];
    __shared__ __align__(16) float stage[32 * 132];
    const int tid  = threadIdx.x;
    const int wave = tid >> 6;
    const int lane = tid & 63;
    const int wm = wave >> 1, wn = wave & 1;

    int nwg = gridDim.x;
    int wg  = blockIdx.x;
    int cpx = nwg >> 3;
    wg = (wg & 7) * cpx + (wg >> 3);
    const int bm = (wg % mblk) * 128;
    const int bn = (wg / mblk) * 128;

    const int sr = tid >> 2;
    const int sc = (tid & 3) * 8;
    const u16* ga0 = A  + (long)(bm + sr) * K + sc;
    const u16* ga1 = A  + (long)(bm + 64 + sr) * K + sc;
    const u16* gb0 = Bm + (long)(bn + sr) * K + sc;
    const u16* gb1 = Bm + (long)(bn + 64 + sr) * K + sc;
    u16* la0 = As + tid * 8;
    u16* la1 = As + 2048 + tid * 8;
    u16* lb0 = Bs + tid * 8;
    u16* lb1 = Bs + 2048 + tid * 8;

    const int fr = lane & 15;
    const int kh = (lane >> 4) * 8;

    f32x4 acc[4][4];
    #pragma unroll
    for (int i = 0; i < 4; ++i)
        #pragma unroll
        for (int j = 0; j < 4; ++j) acc[i][j] = f32x4{0.f, 0.f, 0.f, 0.f};

    for (int k0 = 0; k0 < K; k0 += 32) {
        gload_lds16(ga0 + k0, la0);
        gload_lds16(ga1 + k0, la1);
        gload_lds16(gb0 + k0, lb0);
        gload_lds16(gb1 + k0, lb1);
        __syncthreads();
        bf16x8 af[4], bf[4];
        #pragma unroll
        for (int mi = 0; mi < 4; ++mi)
            af[mi] = *(const bf16x8*)&As[(wm * 64 + mi * 16 + fr) * 32 + kh];
        #pragma unroll
        for (int ni = 0; ni < 4; ++ni)
            bf[ni] = *(const bf16x8*)&Bs[(wn * 64 + ni * 16 + fr) * 32 + kh];
        #pragma unroll
        for (int mi = 0; mi < 4; ++mi)
            #pragma unroll
            for (int ni = 0; ni < 4; ++ni)
                acc[mi][ni] = __builtin_amdgcn_mfma_f32_16x16x32_bf16(af[mi], bf[ni], acc[mi][ni], 0, 0, 0);
        __syncthreads();
    }

    const int r0 = (lane >> 4) * 4;
    float bv[4];
    #pragma unroll
    for (int ni = 0; ni < 4; ++ni) bv[ni] = bias[bn + wn * 64 + ni * 16 + fr];

    #pragma unroll
    for (int mi = 0; mi < 4; ++mi) {
        __syncthreads();
        #pragma unroll
        for (int ni = 0; ni < 4; ++ni) {
            int scol = wn * 64 + ni * 16 + fr;
            #pragma unroll
            for (int j = 0; j < 4; ++j)
                stage[(wm * 16 + r0 + j) * 132 + scol] = acc[mi][ni][j] + bv[ni];
        }
        __syncthreads();
        #pragma unroll
        for (int p = 0; p < 4; ++p) {
            int idx  = p * 256 + tid;
            int srow = idx >> 5;
            int sc4  = (idx & 31) * 4;
            f32x4 v = *(const f32x4*)&stage[srow * 132 + sc4];
            int grow = bm + mi * 16 + (srow & 15) + (srow >> 4) * 64;
            __builtin_nontemporal_store(v, (f32x4*)&C[(long)grow * N + bn + sc4]);
        }
    }
}

// ============================================================================
// FUSED persistent kernel (cooperative, grid 256):
//   blocks 0..63   : GRU producer (r14 v8; hst now t-major agent-atomic)
//   blocks 64..255 : logits consumers (tile j=cid+192k; mt=j/250 tracks prod.)
#define PF 8
__global__ __launch_bounds__(256) void fused(
    const u16* __restrict__ Whh, const float* __restrict__ bhh,
    const float* __restrict__ gi, const float* __restrict__ initp,
    u16* __restrict__ hst,   // [4096][1024] bf16, row = t*64 + b  (t-major)
    u16* __restrict__ hT,    // [64][32][64][32] bf16 k-major
    int* __restrict__ arr, int* __restrict__ rel,
    const u16* __restrict__ Wout, const float* __restrict__ bout,
    float* __restrict__ out)
{
    __builtin_amdgcn_fence(__ATOMIC_ACQUIRE, "agent");   // inv stale L1/L2

    __shared__ __align__(16) char smem[101376];
    const int tid = threadIdx.x;

    if (blockIdx.x < 64) {
        // ------------------- GRU producer -------------------
        u16* Wl  = (u16*)smem;              // 48*1032 u16 = 99072*... (48*1032*2 B)
        u16* h0l = (u16*)(smem + 99072 * 2 - 99072);  // see below
        // layout: Wl occupies 48*1032*2 = 99072 bytes? (u16 count 49536)
        // -> place h0l right after at byte 99072.
        h0l = (u16*)(smem + 99072);
        const int w    = tid >> 6;
        const int lane = tid & 63;
        const int c0   = blockIdx.x * 16;
        const int fr   = lane & 15;
        const int kh   = (lane >> 4) * 8;
        const int r0   = (lane >> 4) * 4;
        const int kb_s = blockIdx.x >> 1;
        const int kio  = (blockIdx.x & 1) * 16;

        for (int ch = tid; ch < 48 * 128; ch += 256) {
            int r  = ch >> 7;
            int cc = (ch & 127) * 8;
            int g  = r >> 4, i = r & 15;
            *(bf16x8*)&Wl[r * 1032 + cc] =
                *(const bf16x8*)&Whh[((long)g * DDsz + c0 + i) * DDsz + cc];
        }
        #pragma unroll
        for (int i = 0; i < 4; ++i) h0l[tid * 4 + i] = f2bf(initp[tid * 4 + i]);
        __syncthreads();

        float hc[4];
        { float v = initp[c0 + fr];
          #pragma unroll
          for (int j = 0; j < 4; ++j) hc[j] = v; }
        const float bR = bhh[c0 + fr];
        const float bZ = bhh[DDsz + c0 + fr];
        const float bN = bhh[2 * DDsz + c0 + fr];

        float gir[4], giz[4], gin_[4];
        #pragma unroll
        for (int j = 0; j < 4; ++j) {
            long gib = ((long)(w * 16 + r0 + j) * Tsz) * G3 + c0 + fr;
            gir[j]  = gi[gib];
            giz[j]  = gi[gib + DDsz];
            gin_[j] = gi[gib + 2 * DDsz];
        }

        for (int t = 0; t < Tsz; ++t) {
            f32x4 acc[3];
            #pragma unroll
            for (int g = 0; g < 3; ++g) acc[g] = f32x4{0.f, 0.f, 0.f, 0.f};

            auto mfma3 = [&](bf16x8 a, int k) {
                bf16x8 wr_ = *(const bf16x8*)&Wl[(0  + fr) * 1032 + k * 32 + kh];
                bf16x8 wz_ = *(const bf16x8*)&Wl[(16 + fr) * 1032 + k * 32 + kh];
                bf16x8 wn_ = *(const bf16x8*)&Wl[(32 + fr) * 1032 + k * 32 + kh];
                acc[0] = __builtin_amdgcn_mfma_f32_16x16x32_bf16(a, wr_, acc[0], 0, 0, 0);
                acc[1] = __builtin_amdgcn_mfma_f32_16x16x32_bf16(a, wz_, acc[1], 0, 0, 0);
                acc[2] = __builtin_amdgcn_mfma_f32_16x16x32_bf16(a, wn_, acc[2], 0, 0, 0);
            };

            if (t == 0) {
                #pragma unroll
                for (int k = 0; k < 32; ++k) mfma3(*(const bf16x8*)&h0l[k * 32 + kh], k);
            } else {
                const u16* q0 = hT + ((long)(t - 1) * 32 * 64 + w * 16) * 32 + fr * 32 + kh;
                bf16x8 p0[PF];
                #pragma unroll
                for (int p = 0; p < PF; ++p) p0[p] = *(const bf16x8*)(q0 + p * 2048);
                #pragma unroll
                for (int k = 0; k < 32; ++k) {
                    bf16x8 a = p0[k & (PF - 1)];
                    if (k < 32 - PF) p0[k & (PF - 1)] = *(const bf16x8*)(q0 + (k + PF) * 2048);
                    mfma3(a, k);
                }
            }

            // gates + dual agent-atomic h store (hT k-major + hst t-major)
            #pragma unroll
            for (int j = 0; j < 4; ++j) {
                int b = w * 16 + r0 + j;
                float r = fast_sigmoid(gir[j] + acc[0][j] + bR);
                float z = fast_sigmoid(giz[j] + acc[1][j] + bZ);
                float n = fast_tanh(gin_[j] + r * (acc[2][j] + bN));
                float h = (1.f - z) * n + z * hc[j];
                hc[j] = h;
                int hb = (int)f2bf(h);
                int pb = __shfl_xor(hb, 1, 64);
                if (!(fr & 1)) {
                    u32 val = ((u32)pb << 16) | (u32)hb;
                    __hip_atomic_store(
                        (u32*)(hT + (((long)t * 32 + kb_s) * 64 + b) * 32 + kio + fr), val,
                        __ATOMIC_RELAXED, __HIP_MEMORY_SCOPE_AGENT);
                    __hip_atomic_store(
                        (u32*)(hst + ((long)t * Bsz + b) * DDsz + c0 + fr), val,
                        __ATOMIC_RELAXED, __HIP_MEMORY_SCOPE_AGENT);
                }
            }

            asm volatile("" ::: "memory");
            if (t != Tsz - 1) {
                int tp = t + 1;
                #pragma unroll
                for (int j = 0; j < 4; ++j) {
                    long gib = ((long)(w * 16 + r0 + j) * Tsz + tp) * G3 + c0 + fr;
                    gir[j]  = gi[gib];
                    giz[j]  = gi[gib + DDsz];
                    gin_[j] = gi[gib + 2 * DDsz];
                }
                asm volatile("s_waitcnt vmcnt(12)" ::: "memory"); // drain h stores only
            } else {
                asm volatile("s_waitcnt vmcnt(0)" ::: "memory");  // final full drain
            }
            __builtin_amdgcn_s_barrier();
            if (tid == 0) {
                __hip_atomic_fetch_add(&arr[(blockIdx.x & 7) << 4], 1,
                                       __ATOMIC_RELAXED, __HIP_MEMORY_SCOPE_AGENT);
                if (blockIdx.x == 0) {
                    const int tgt = 64 * (t + 1);
                    for (;;) {
                        int s = 0;
                        #pragma unroll
                        for (int g = 0; g < 8; ++g)
                            s += __hip_atomic_load(&arr[g << 4], __ATOMIC_RELAXED,
                                                   __HIP_MEMORY_SCOPE_AGENT);
                        if (s >= tgt) break;
                    }
                    #pragma unroll
                    for (int g = 0; g < 8; ++g)
                        __hip_atomic_store(&rel[g << 4], t + 1,
                                           __ATOMIC_RELAXED, __HIP_MEMORY_SCOPE_AGENT);
                } else {
                    while (__hip_atomic_load(&rel[(blockIdx.x & 7) << 4],
                                             __ATOMIC_RELAXED,
                                             __HIP_MEMORY_SCOPE_AGENT) < t + 1) { }
                }
            }
            __syncthreads();
        }
    } else {
        // ------------------- logits consumer -------------------
        u16*   As    = (u16*)smem;                 //  8192 B
        u16*   Bs    = (u16*)(smem + 8192);        //  8192 B
        float* stage = (float*)(smem + 16384);     // 16896 B
        const int cid  = blockIdx.x - 64;          // 0..191
        const int wave = tid >> 6;
        const int lane = tid & 63;
        const int wm = wave >> 1, wn = wave & 1;
        const int sr = tid >> 2;
        const int sc = (tid & 3) * 8;
        const int fr = lane & 15;
        const int kh = (lane >> 4) * 8;
        const int r0 = (lane >> 4) * 4;
        u16* la0 = As + tid * 8;
        u16* la1 = As + 2048 + tid * 8;
        u16* lb0 = Bs + tid * 8;
        u16* lb1 = Bs + 2048 + tid * 8;

        int lastmt = -1;
        for (int j = cid; j < NMT * NTT; j += NCONS) {
            int mt = j / NTT;
            int nt = j - mt * NTT;
            if (mt != lastmt) {
                if (tid == 0) {
                    while (__hip_atomic_load(&rel[(cid & 7) << 4], __ATOMIC_RELAXED,
                                             __HIP_MEMORY_SCOPE_AGENT) < 2 * mt + 2)
                        __builtin_amdgcn_s_sleep(8);
                }
                __syncthreads();
                lastmt = mt;
            }
            const int bm = mt * 128;
            const int bn = nt * 128;
            const u16* ga0 = hst  + (long)(bm + sr) * DDsz + sc;
            const u16* ga1 = hst  + (long)(bm + 64 + sr) * DDsz + sc;
            const u16* gb0 = Wout + (long)(bn + sr) * DDsz + sc;
            const u16* gb1 = Wout + (long)(bn + 64 + sr) * DDsz + sc;

            f32x4 acc[4][4];
            #pragma unroll
            for (int i = 0; i < 4; ++i)
                #pragma unroll
                for (int jj = 0; jj < 4; ++jj) acc[i][jj] = f32x4{0.f, 0.f, 0.f, 0.f};

            for (int k0 = 0; k0 < DDsz; k0 += 32) {
                gload_lds16(ga0 + k0, la0);
                gload_lds16(ga1 + k0, la1);
                gload_lds16(gb0 + k0, lb0);
                gload_lds16(gb1 + k0, lb1);
                __syncthreads();
                bf16x8 af[4], bf[4];
                #pragma unroll
                for (int mi = 0; mi < 4; ++mi)
                    af[mi] = *(const bf16x8*)&As[(wm * 64 + mi * 16 + fr) * 32 + kh];
                #pragma unroll
                for (int ni = 0; ni < 4; ++ni)
                    bf[ni] = *(const bf16x8*)&Bs[(wn * 64 + ni * 16 + fr) * 32 + kh];
                #pragma unroll
                for (int mi = 0; mi < 4; ++mi)
                    #pragma unroll
                    for (int ni = 0; ni < 4; ++ni)
                        acc[mi][ni] = __builtin_amdgcn_mfma_f32_16x16x32_bf16(af[mi], bf[ni], acc[mi][ni], 0, 0, 0);
                __syncthreads();
            }

            float bv[4];
            #pragma unroll
            for (int ni = 0; ni < 4; ++ni) bv[ni] = bout[bn + wn * 64 + ni * 16 + fr];

            #pragma unroll
            for (int mi = 0; mi < 4; ++mi) {
                __syncthreads();
                #pragma unroll
                for (int ni = 0; ni < 4; ++ni) {
                    int scol = wn * 64 + ni * 16 + fr;
                    #pragma unroll
                    for (int jj = 0; jj < 4; ++jj)
                        stage[(wm * 16 + r0 + jj) * 132 + scol] = acc[mi][ni][jj] + bv[ni];
                }
                __syncthreads();
                #pragma unroll
                for (int p = 0; p < 4; ++p) {
                    int idx  = p * 256 + tid;
                    int srow = idx >> 5;
                    int sc4  = (idx & 31) * 4;
                    f32x4 v = *(const f32x4*)&stage[srow * 132 + sc4];
                    int r = bm + mi * 16 + (srow & 15) + (srow >> 4) * 64; // hst row (t*64+b)
                    int orow = ((r & 63) << 6) | (r >> 6);                 // out row (b*64+t)
                    __builtin_nontemporal_store(v, (f32x4*)&out[(long)orow * Vsz + bn + sc4]);
                }
            }
        }
    }
}

extern "C" void kernel_launch(void* const* d_in, const int* in_sizes, int n_in,
                              void* d_out, int out_size, void* d_ws, size_t ws_size,
                              hipStream_t stream) {
    const float* ctx    = (const float*)d_in[0];
    const int*   labels = (const int*)  d_in[1];
    const float* emb    = (const float*)d_in[2];
    const float* W_ih   = (const float*)d_in[3];
    const float* b_ih   = (const float*)d_in[4];
    const float* W_hh   = (const float*)d_in[5];
    const float* b_hh   = (const float*)d_in[6];
    const float* initp  = (const float*)d_in[7];
    const float* W_out  = (const float*)d_in[8];
    const float* b_out  = (const float*)d_in[9];
    const int*   bos    = (const int*)  d_in[10];
    float* out = (float*)d_out;

    char* ws = (char*)d_ws;
    u16*   Xbf    = (u16*)  (ws + 0L);            //  8,388,608
    float* gi     = (float*)(ws + 8388608L);      // 50,331,648
    u16*   hst    = (u16*)  (ws + 58720256L);     //  8,388,608  (t-major)
    u16*   hT     = (u16*)  (ws + 67108864L);     //  8,388,608  (k-major)
    u16*   Wih_b  = (u16*)  (ws + 75497472L);     //  6,291,456
    u16*   Whh_b  = (u16*)  (ws + 81788928L);     //  6,291,456
    u16*   Wout_b = (u16*)  (ws + 88080384L);     // 65,536,000 -> 153,616,384
    int*   arr    = (int*)  (ws + 153616384L);    // 512 B arrival counters
    int*   rel    = (int*)  (ws + 153617408L);    // 512 B release lines

    (void)hipMemsetAsync(arr, 0, 2048, stream);   // zero arr + rel

    long n1 = (long)G3 * DIN;          // 3,145,728
    long n2 = (long)Vsz * DDsz;        // 32,768,000
    f32_to_bf16<<<(unsigned)(n1 / 4 / 256), 256, 0, stream>>>(W_ih, Wih_b, n1);
    f32_to_bf16<<<(unsigned)(n1 / 4 / 256), 256, 0, stream>>>(W_hh, Whh_b, n1);
    f32_to_bf16<<<(unsigned)(n2 / 4 / 256), 256, 0, stream>>>(W_out, Wout_b, n2);

    build_x<<<Bsz * Tsz, 128, 0, stream>>>(emb, ctx, labels, bos, Xbf);

    // gi = X @ W_ih^T + b_ih   (4096 x 3072), grid 768 (%8==0)
    gemm128<<<(4096 / 128) * (G3 / 128), 256, 0, stream>>>(
        Xbf, Wih_b, b_ih, gi, G3, DIN, 4096 / 128);

    // fused producer/consumer: 64 GRU blocks + 192 logits blocks (cooperative)
    {
        const u16* Whh_c = Whh_b; const float* bhh_c = b_hh;
        const float* gi_c = gi;   const float* init_c = initp;
        u16* hst_c = hst;         u16* hT_c = hT;
        int* arr_c = arr;         int* rel_c = rel;
        const u16* Wout_c = Wout_b; const float* bout_c = b_out;
        float* out_c = out;
        void* kargs[] = {&Whh_c, &bhh_c, &gi_c, &init_c, &hst_c, &hT_c,
                         &arr_c, &rel_c, &Wout_c, &bout_c, &out_c};
        (void)hipLaunchCooperativeKernel((const void*)fused, dim3(256), dim3(256),
                                         kargs, 0, stream);
    }
}

// Round 17
// 877.669 us; speedup vs baseline: 1.3858x; 1.0911x over previous
//
#include <hip/hip_runtime.h>

// ---- sizes (fixed by the problem) ----
#define Bsz 64
#define Tsz 64
#define Vsz 32000
#define DEsz 512
#define DDsz 1024
#define DCsz 512
#define DIN 1024     // DE+DC
#define G3 3072      // 3*DD

typedef unsigned short u16;
typedef unsigned int   u32;
typedef unsigned long long u64;
typedef __attribute__((ext_vector_type(8))) __bf16 bf16x8;
typedef __attribute__((ext_vector_type(4))) float f32x4;

__device__ __forceinline__ u16 f2bf(float f) {
    union { float f; unsigned int u; } v; v.f = f;
    unsigned int r = v.u + 0x7fffu + ((v.u >> 16) & 1u);  // RNE
    return (u16)(r >> 16);
}

__device__ __forceinline__ void gload_lds16(const u16* g, u16* l) {
    __builtin_amdgcn_global_load_lds(
        (const __attribute__((address_space(1))) void*)g,
        (__attribute__((address_space(3))) void*)l, 16, 0, 0);
}

__device__ __forceinline__ float fast_sigmoid(float x) {
    float xc = fminf(fmaxf(x, -30.f), 30.f);
    return 1.f / (1.f + __expf(-xc));
}
__device__ __forceinline__ float fast_tanh(float x) {
    float xc = fminf(fmaxf(x, -15.f), 15.f);
    float e = __expf(2.f * xc);
    return (e - 1.f) / (e + 1.f);
}

// ---------- f32 -> bf16 bulk convert ----------
__global__ void f32_to_bf16(const float* __restrict__ src, u16* __restrict__ dst, long n) {
    long i = ((long)blockIdx.x * blockDim.x + threadIdx.x) * 4;
    if (i + 3 < n) {
        float4 v = *(const float4*)&src[i];
        dst[i + 0] = f2bf(v.x);
        dst[i + 1] = f2bf(v.y);
        dst[i + 2] = f2bf(v.z);
        dst[i + 3] = f2bf(v.w);
    }
}

// ---------- build X = concat(emb[token], context) bf16, row = b*T + t ----------
__global__ void build_x(const float* __restrict__ emb, const float* __restrict__ ctx,
                        const int* __restrict__ labels, const int* __restrict__ bos,
                        u16* __restrict__ X) {
    int i = blockIdx.x;            // 0..4095 = b*64 + t
    int b = i >> 6;
    int t = i & 63;
    int tok = (t == 0) ? *bos : labels[b * Tsz + (t - 1)];
    const float* s0 = emb + (long)tok * DEsz;
    const float* s1 = ctx + (long)b * DCsz;
    u16* dst = X + (long)i * DIN;
    for (int c = threadIdx.x; c < DEsz; c += blockDim.x) {
        dst[c]        = f2bf(s0[c]);
        dst[DEsz + c] = f2bf(s1[c]);
    }
}

// ---------- 128x128 GEMM (gi): LDS-staged FULL-LINE stores ----------
__global__ __launch_bounds__(256) void gemm128(
    const u16* __restrict__ A, const u16* __restrict__ Bm,
    const float* __restrict__ bias, float* __restrict__ C,
    int N, int K, int mblk)
{
    __shared__ __align__(16) u16 As[128 * 32];
    __shared__ __align__(16) u16 Bs[128 * 32];
    __shared__ __align__(16) float stage[32 * 132];
    const int tid  = threadIdx.x;
    const int wave = tid >> 6;
    const int lane = tid & 63;
    const int wm = wave >> 1, wn = wave & 1;

    int nwg = gridDim.x;
    int wg  = blockIdx.x;
    int cpx = nwg >> 3;
    wg = (wg & 7) * cpx + (wg >> 3);
    const int bm = (wg % mblk) * 128;
    const int bn = (wg / mblk) * 128;

    const int sr = tid >> 2;
    const int sc = (tid & 3) * 8;
    const u16* ga0 = A  + (long)(bm + sr) * K + sc;
    const u16* ga1 = A  + (long)(bm + 64 + sr) * K + sc;
    const u16* gb0 = Bm + (long)(bn + sr) * K + sc;
    const u16* gb1 = Bm + (long)(bn + 64 + sr) * K + sc;
    u16* la0 = As + tid * 8;
    u16* la1 = As + 2048 + tid * 8;
    u16* lb0 = Bs + tid * 8;
    u16* lb1 = Bs + 2048 + tid * 8;

    const int fr = lane & 15;
    const int kh = (lane >> 4) * 8;

    f32x4 acc[4][4];
    #pragma unroll
    for (int i = 0; i < 4; ++i)
        #pragma unroll
        for (int j = 0; j < 4; ++j) acc[i][j] = f32x4{0.f, 0.f, 0.f, 0.f};

    for (int k0 = 0; k0 < K; k0 += 32) {
        gload_lds16(ga0 + k0, la0);
        gload_lds16(ga1 + k0, la1);
        gload_lds16(gb0 + k0, lb0);
        gload_lds16(gb1 + k0, lb1);
        __syncthreads();
        bf16x8 af[4], bf[4];
        #pragma unroll
        for (int mi = 0; mi < 4; ++mi)
            af[mi] = *(const bf16x8*)&As[(wm * 64 + mi * 16 + fr) * 32 + kh];
        #pragma unroll
        for (int ni = 0; ni < 4; ++ni)
            bf[ni] = *(const bf16x8*)&Bs[(wn * 64 + ni * 16 + fr) * 32 + kh];
        #pragma unroll
        for (int mi = 0; mi < 4; ++mi)
            #pragma unroll
            for (int ni = 0; ni < 4; ++ni)
                acc[mi][ni] = __builtin_amdgcn_mfma_f32_16x16x32_bf16(af[mi], bf[ni], acc[mi][ni], 0, 0, 0);
        __syncthreads();
    }

    const int r0 = (lane >> 4) * 4;
    float bv[4];
    #pragma unroll
    for (int ni = 0; ni < 4; ++ni) bv[ni] = bias[bn + wn * 64 + ni * 16 + fr];

    #pragma unroll
    for (int mi = 0; mi < 4; ++mi) {
        __syncthreads();
        #pragma unroll
        for (int ni = 0; ni < 4; ++ni) {
            int scol = wn * 64 + ni * 16 + fr;
            #pragma unroll
            for (int j = 0; j < 4; ++j)
                stage[(wm * 16 + r0 + j) * 132 + scol] = acc[mi][ni][j] + bv[ni];
        }
        __syncthreads();
        #pragma unroll
        for (int p = 0; p < 4; ++p) {
            int idx  = p * 256 + tid;
            int srow = idx >> 5;
            int sc4  = (idx & 31) * 4;
            f32x4 v = *(const f32x4*)&stage[srow * 132 + sc4];
            int grow = bm + mi * 16 + (srow & 15) + (srow >> 4) * 64;
            __builtin_nontemporal_store(v, (f32x4*)&C[(long)grow * N + bn + sc4]);
        }
    }
}

// ---------- logits GEMM: A staged DIRECTLY from k-major hT; out[b][t][v] ----------
// hT[t][kb][b][ki]: A-row r (=t*64+b) k-slice [k0+sc, +8) is contiguous at
// t*65536 + b*32 + sc + k0*64. Epilogue permutes row r -> out row (b<<6)|t.
__global__ __launch_bounds__(256) void gemm_hT(
    const u16* __restrict__ hT, const u16* __restrict__ Bm,
    const float* __restrict__ bias, float* __restrict__ C,
    int N, int mblk)
{
    __shared__ __align__(16) u16 As[128 * 32];
    __shared__ __align__(16) u16 Bs[128 * 32];
    __shared__ __align__(16) float stage[32 * 132];
    const int tid  = threadIdx.x;
    const int wave = tid >> 6;
    const int lane = tid & 63;
    const int wm = wave >> 1, wn = wave & 1;

    int nwg = gridDim.x;
    int wg  = blockIdx.x;
    int cpx = nwg >> 3;
    wg = (wg & 7) * cpx + (wg >> 3);
    const int bm = (wg % mblk) * 128;
    const int bn = (wg / mblk) * 128;

    const int sr = tid >> 2;
    const int sc = (tid & 3) * 8;
    const int rA0 = bm + sr, rA1 = bm + 64 + sr;
    const u16* ga0 = hT + (long)(rA0 >> 6) * 65536 + (rA0 & 63) * 32 + sc;
    const u16* ga1 = hT + (long)(rA1 >> 6) * 65536 + (rA1 & 63) * 32 + sc;
    const u16* gb0 = Bm + (long)(bn + sr) * DDsz + sc;
    const u16* gb1 = Bm + (long)(bn + 64 + sr) * DDsz + sc;
    u16* la0 = As + tid * 8;
    u16* la1 = As + 2048 + tid * 8;
    u16* lb0 = Bs + tid * 8;
    u16* lb1 = Bs + 2048 + tid * 8;

    const int fr = lane & 15;
    const int kh = (lane >> 4) * 8;

    f32x4 acc[4][4];
    #pragma unroll
    for (int i = 0; i < 4; ++i)
        #pragma unroll
        for (int j = 0; j < 4; ++j) acc[i][j] = f32x4{0.f, 0.f, 0.f, 0.f};

    for (int k0 = 0; k0 < DDsz; k0 += 32) {
        gload_lds16(ga0 + k0 * 64, la0);     // hT: k0-stride = 2048 u16 = k0*64
        gload_lds16(ga1 + k0 * 64, la1);
        gload_lds16(gb0 + k0, lb0);
        gload_lds16(gb1 + k0, lb1);
        __syncthreads();
        bf16x8 af[4], bf[4];
        #pragma unroll
        for (int mi = 0; mi < 4; ++mi)
            af[mi] = *(const bf16x8*)&As[(wm * 64 + mi * 16 + fr) * 32 + kh];
        #pragma unroll
        for (int ni = 0; ni < 4; ++ni)
            bf[ni] = *(const bf16x8*)&Bs[(wn * 64 + ni * 16 + fr) * 32 + kh];
        #pragma unroll
        for (int mi = 0; mi < 4; ++mi)
            #pragma unroll
            for (int ni = 0; ni < 4; ++ni)
                acc[mi][ni] = __builtin_amdgcn_mfma_f32_16x16x32_bf16(af[mi], bf[ni], acc[mi][ni], 0, 0, 0);
        __syncthreads();
    }

    const int r0 = (lane >> 4) * 4;
    float bv[4];
    #pragma unroll
    for (int ni = 0; ni < 4; ++ni) bv[ni] = bias[bn + wn * 64 + ni * 16 + fr];

    #pragma unroll
    for (int mi = 0; mi < 4; ++mi) {
        __syncthreads();
        #pragma unroll
        for (int ni = 0; ni < 4; ++ni) {
            int scol = wn * 64 + ni * 16 + fr;
            #pragma unroll
            for (int j = 0; j < 4; ++j)
                stage[(wm * 16 + r0 + j) * 132 + scol] = acc[mi][ni][j] + bv[ni];
        }
        __syncthreads();
        #pragma unroll
        for (int p = 0; p < 4; ++p) {
            int idx  = p * 256 + tid;
            int srow = idx >> 5;
            int sc4  = (idx & 31) * 4;
            f32x4 v = *(const f32x4*)&stage[srow * 132 + sc4];
            int r    = bm + mi * 16 + (srow & 15) + (srow >> 4) * 64;  // t*64+b
            int orow = ((r & 63) << 6) | (r >> 6);                     // b*64+t
            __builtin_nontemporal_store(v, (f32x4*)&C[(long)orow * N + bn + sc4]);
        }
    }
}

// ---------- persistent GRU v11: per-wave decoupled dual-chain barriers ----------
// 64 blocks x 256 thr. Block owns 16 hidden cols x 3 gates; wave w owns batch
// rows [16w,16w+16). Chain = w>>1 (rows 0-31 / 32-63 are independent GRUs).
// Each WAVE drains/arrives/polls its own chain's barrier: 128 arrivals/chain
// (64 blocks x 2 waves); block0 waves 0/2 sum+release. NO per-step s_barrier.
// hT [t][kb(32)][b(64)][ki(32)]; single agent-atomic store (hst removed).
#define PF 8
__global__ __launch_bounds__(256) void gru_persist(
    const u16* __restrict__ Whh,     // [3072][1024] bf16
    const float* __restrict__ bhh,   // [3072]
    const float* __restrict__ gi,    // [4096][3072] f32, row = b*T + t
    const float* __restrict__ initp, // [1024]
    u16* __restrict__ hT,            // [64][32][64][32] bf16 k-major
    int* __restrict__ arr,           // 16 lines x 64B (chain c: lines c*8+..)
    int* __restrict__ rel)           // 2 lines x 64B
{
    __builtin_amdgcn_fence(__ATOMIC_ACQUIRE, "agent");   // inv stale L2 (prior replay)

    __shared__ __align__(16) u16 Wl[48 * 1032];   // +8 pad
    __shared__ __align__(16) u16 h0l[1024];
    const int tid  = threadIdx.x;
    const int w    = tid >> 6;       // wave 0..3 -> batch quarter
    const int lane = tid & 63;
    const int c0   = blockIdx.x * 16;
    const int fr   = lane & 15;
    const int kh   = (lane >> 4) * 8;
    const int r0   = (lane >> 4) * 4;
    const int kb_s = blockIdx.x >> 1;
    const int kio  = (blockIdx.x & 1) * 16;
    const int chain  = w >> 1;                                   // 0 or 1
    const int myline = ((chain << 3) | (blockIdx.x & 7)) << 4;   // arr line

    for (int ch = tid; ch < 48 * 128; ch += 256) {
        int r  = ch >> 7;
        int cc = (ch & 127) * 8;
        int g  = r >> 4, i = r & 15;
        *(bf16x8*)&Wl[r * 1032 + cc] =
            *(const bf16x8*)&Whh[((long)g * DDsz + c0 + i) * DDsz + cc];
    }
    #pragma unroll
    for (int i = 0; i < 4; ++i) h0l[tid * 4 + i] = f2bf(initp[tid * 4 + i]);
    __syncthreads();    // ONLY block-wide sync (W/h0 preload)

    float hc[4];
    { float v = initp[c0 + fr];
      #pragma unroll
      for (int j = 0; j < 4; ++j) hc[j] = v; }
    const float bR = bhh[c0 + fr];
    const float bZ = bhh[DDsz + c0 + fr];
    const float bN = bhh[2 * DDsz + c0 + fr];

    // gi(t=0) prefetch
    float gir[4], giz[4], gin_[4];
    #pragma unroll
    for (int j = 0; j < 4; ++j) {
        long gib = ((long)(w * 16 + r0 + j) * Tsz) * G3 + c0 + fr;
        gir[j]  = gi[gib];
        giz[j]  = gi[gib + DDsz];
        gin_[j] = gi[gib + 2 * DDsz];
    }

    for (int t = 0; t < Tsz; ++t) {
        f32x4 acc[3];
        #pragma unroll
        for (int g = 0; g < 3; ++g) acc[g] = f32x4{0.f, 0.f, 0.f, 0.f};

        auto mfma3 = [&](bf16x8 a, int k) {
            bf16x8 wr_ = *(const bf16x8*)&Wl[(0  + fr) * 1032 + k * 32 + kh];
            bf16x8 wz_ = *(const bf16x8*)&Wl[(16 + fr) * 1032 + k * 32 + kh];
            bf16x8 wn_ = *(const bf16x8*)&Wl[(32 + fr) * 1032 + k * 32 + kh];
            acc[0] = __builtin_amdgcn_mfma_f32_16x16x32_bf16(a, wr_, acc[0], 0, 0, 0);
            acc[1] = __builtin_amdgcn_mfma_f32_16x16x32_bf16(a, wz_, acc[1], 0, 0, 0);
            acc[2] = __builtin_amdgcn_mfma_f32_16x16x32_bf16(a, wn_, acc[2], 0, 0, 0);
        };

        if (t == 0) {
            #pragma unroll
            for (int k = 0; k < 32; ++k) mfma3(*(const bf16x8*)&h0l[k * 32 + kh], k);
        } else {
            // COALESCED: k-step reads 1024B contiguous per wave from hT(t-1)
            const u16* q0 = hT + ((long)(t - 1) * 32 * 64 + w * 16) * 32 + fr * 32 + kh;
            bf16x8 p0[PF];
            #pragma unroll
            for (int p = 0; p < PF; ++p) p0[p] = *(const bf16x8*)(q0 + p * 2048);
            #pragma unroll
            for (int k = 0; k < 32; ++k) {
                bf16x8 a = p0[k & (PF - 1)];
                if (k < 32 - PF) p0[k & (PF - 1)] = *(const bf16x8*)(q0 + (k + PF) * 2048);
                mfma3(a, k);
            }
        }

        // gates + single agent-atomic h store (k-major hT only)
        #pragma unroll
        for (int j = 0; j < 4; ++j) {
            int b = w * 16 + r0 + j;
            float r = fast_sigmoid(gir[j] + acc[0][j] + bR);
            float z = fast_sigmoid(giz[j] + acc[1][j] + bZ);
            float n = fast_tanh(gin_[j] + r * (acc[2][j] + bN));
            float h = (1.f - z) * n + z * hc[j];
            hc[j] = h;
            int hb = (int)f2bf(h);
            int pb = __shfl_xor(hb, 1, 64);        // partner column bits
            if (!(fr & 1)) {
                u32 val = ((u32)pb << 16) | (u32)hb;
                __hip_atomic_store(
                    (u32*)(hT + (((long)t * 32 + kb_s) * 64 + b) * 32 + kio + fr), val,
                    __ATOMIC_RELAXED, __HIP_MEMORY_SCOPE_AGENT);
            }
        }

        if (t != Tsz - 1) {
            asm volatile("" ::: "memory");   // pin: h stores issue before gi loads

            // gi(t+1): 12 loads stay IN FLIGHT across the barrier
            int tp = t + 1;
            #pragma unroll
            for (int j = 0; j < 4; ++j) {
                long gib = ((long)(w * 16 + r0 + j) * Tsz + tp) * G3 + c0 + fr;
                gir[j]  = gi[gib];
                giz[j]  = gi[gib + DDsz];
                gin_[j] = gi[gib + 2 * DDsz];
            }

            // per-wave drain: waits the 4 h stores (gi loads stay outstanding)
            asm volatile("s_waitcnt vmcnt(12)" ::: "memory");

            // per-wave chain barrier: 128 arrivals (64 blocks x 2 waves)
            if (lane == 0) {
                __hip_atomic_fetch_add(&arr[myline], 1,
                                       __ATOMIC_RELAXED, __HIP_MEMORY_SCOPE_AGENT);
                if (blockIdx.x == 0 && (w & 1) == 0) {      // waves 0,2 release
                    const int tgt = 128 * (t + 1);
                    for (;;) {
                        int s = 0;
                        #pragma unroll
                        for (int g = 0; g < 8; ++g)
                            s += __hip_atomic_load(&arr[((chain << 3) | g) << 4],
                                                   __ATOMIC_RELAXED,
                                                   __HIP_MEMORY_SCOPE_AGENT);
                        if (s >= tgt) break;
                    }
                    __hip_atomic_store(&rel[chain << 4], t + 1,
                                       __ATOMIC_RELAXED, __HIP_MEMORY_SCOPE_AGENT);
                } else {
                    while (__hip_atomic_load(&rel[chain << 4], __ATOMIC_RELAXED,
                                             __HIP_MEMORY_SCOPE_AGENT) < t + 1) { }
                }
            }
            asm volatile("" ::: "memory");   // no hT load hoisting above the poll
        }
    }
}

extern "C" void kernel_launch(void* const* d_in, const int* in_sizes, int n_in,
                              void* d_out, int out_size, void* d_ws, size_t ws_size,
                              hipStream_t stream) {
    const float* ctx    = (const float*)d_in[0];
    const int*   labels = (const int*)  d_in[1];
    const float* emb    = (const float*)d_in[2];
    const float* W_ih   = (const float*)d_in[3];
    const float* b_ih   = (const float*)d_in[4];
    const float* W_hh   = (const float*)d_in[5];
    const float* b_hh   = (const float*)d_in[6];
    const float* initp  = (const float*)d_in[7];
    const float* W_out  = (const float*)d_in[8];
    const float* b_out  = (const float*)d_in[9];
    const int*   bos    = (const int*)  d_in[10];
    float* out = (float*)d_out;

    char* ws = (char*)d_ws;
    u16*   Xbf    = (u16*)  (ws + 0L);            //  8,388,608
    float* gi     = (float*)(ws + 8388608L);      // 50,331,648
    u16*   hT     = (u16*)  (ws + 67108864L);     //  8,388,608  (k-major)
    u16*   Wih_b  = (u16*)  (ws + 75497472L);     //  6,291,456
    u16*   Whh_b  = (u16*)  (ws + 81788928L);     //  6,291,456
    u16*   Wout_b = (u16*)  (ws + 88080384L);     // 65,536,000 -> 153,616,384
    int*   arr    = (int*)  (ws + 153616384L);    // 1024 B (16 lines)
    int*   rel    = (int*)  (ws + 153617408L);    // 128 B (2 lines)

    (void)hipMemsetAsync(arr, 0, 2048, stream);   // zero arr + rel

    long n1 = (long)G3 * DIN;          // 3,145,728
    long n2 = (long)Vsz * DDsz;        // 32,768,000
    f32_to_bf16<<<(unsigned)(n1 / 4 / 256), 256, 0, stream>>>(W_ih, Wih_b, n1);
    f32_to_bf16<<<(unsigned)(n1 / 4 / 256), 256, 0, stream>>>(W_hh, Whh_b, n1);
    f32_to_bf16<<<(unsigned)(n2 / 4 / 256), 256, 0, stream>>>(W_out, Wout_b, n2);

    build_x<<<Bsz * Tsz, 128, 0, stream>>>(emb, ctx, labels, bos, Xbf);

    // gi = X @ W_ih^T + b_ih   (4096 x 3072), grid 768 (%8==0)
    gemm128<<<(4096 / 128) * (G3 / 128), 256, 0, stream>>>(
        Xbf, Wih_b, b_ih, gi, G3, DIN, 4096 / 128);

    // 64 recurrent steps in ONE persistent launch (dual-chain, per-wave sync)
    gru_persist<<<DDsz / 16, 256, 0, stream>>>(Whh_b, b_hh, gi, initp, hT, arr, rel);

    // logits = hT @ W_out^T + b_out -> out[b][t][v], grid 8000 (%8==0)
    gemm_hT<<<(4096 / 128) * (Vsz / 128), 256, 0, stream>>>(
        hT, Wout_b, b_out, out, Vsz, 4096 / 128);
}